// Round 1
// baseline (4706.477 us; speedup 1.0000x reference)
//
#include <hip/hip_runtime.h>
#include <hip/hip_bf16.h>

#define BB 2
#define SS 2048
#define DD 768
#define HH 12
#define HD 64
#define DFF 3072
#define NROW (BB * SS)   // 4096
#define LN_EPS 1e-5f

// ---------------- block-wide reductions (256 threads = 4 waves of 64) -------
__device__ __forceinline__ float block_sum(float v, float* red) {
    __syncthreads();                       // protect red[] reuse across calls
    #pragma unroll
    for (int off = 32; off > 0; off >>= 1) v += __shfl_down(v, off, 64);
    if ((threadIdx.x & 63) == 0) red[threadIdx.x >> 6] = v;
    __syncthreads();
    if (threadIdx.x == 0) red[0] = red[0] + red[1] + red[2] + red[3];
    __syncthreads();
    return red[0];
}

__device__ __forceinline__ float block_max(float v, float* red) {
    __syncthreads();
    #pragma unroll
    for (int off = 32; off > 0; off >>= 1) v = fmaxf(v, __shfl_down(v, off, 64));
    if ((threadIdx.x & 63) == 0) red[threadIdx.x >> 6] = v;
    __syncthreads();
    if (threadIdx.x == 0) red[0] = fmaxf(fmaxf(red[0], red[1]), fmaxf(red[2], red[3]));
    __syncthreads();
    return red[0];
}

// ---------------- generic fp32 GEMM: C[M=4096 x N] = A[4096 x K] @ W[K x N] + bias
// grid = (N/64, 4096/64), block = 256. Optional ReLU.
__global__ __launch_bounds__(256) void gemm_bias_kernel(
        const float* __restrict__ A, const float* __restrict__ W,
        const float* __restrict__ bias, float* __restrict__ C,
        int N, int K, int relu) {
    __shared__ float As[16][64];      // transposed A tile: As[k][m]
    __shared__ float Bs[16][64];      // Bs[k][n]
    const int tid = threadIdx.x;
    const int tx = tid & 15;          // 0..15 -> col groups of 4
    const int ty = tid >> 4;          // 0..15 -> row groups of 4
    const int blockRow = blockIdx.y * 64;
    const int blockCol = blockIdx.x * 64;

    float acc[4][4] = {{0.f}};

    const int ar = tid >> 2;                 // 0..63 (A tile row)
    const int ac4 = (tid & 3) << 2;          // 0,4,8,12 (A tile col)
    const int br = tid >> 4;                 // 0..15 (W tile row)
    const int bc4 = (tid & 15) << 2;         // 0..60 (W tile col)

    for (int k0 = 0; k0 < K; k0 += 16) {
        float4 a = *(const float4*)&A[(size_t)(blockRow + ar) * K + k0 + ac4];
        As[ac4 + 0][ar] = a.x;
        As[ac4 + 1][ar] = a.y;
        As[ac4 + 2][ar] = a.z;
        As[ac4 + 3][ar] = a.w;
        *(float4*)&Bs[br][bc4] = *(const float4*)&W[(size_t)(k0 + br) * N + blockCol + bc4];
        __syncthreads();
        #pragma unroll
        for (int kk = 0; kk < 16; kk++) {
            float av[4], bv[4];
            #pragma unroll
            for (int i = 0; i < 4; i++) av[i] = As[kk][ty * 4 + i];
            #pragma unroll
            for (int j = 0; j < 4; j++) bv[j] = Bs[kk][tx * 4 + j];
            #pragma unroll
            for (int i = 0; i < 4; i++)
                #pragma unroll
                for (int j = 0; j < 4; j++)
                    acc[i][j] = fmaf(av[i], bv[j], acc[i][j]);
        }
        __syncthreads();
    }

    #pragma unroll
    for (int i = 0; i < 4; i++) {
        const int row = blockRow + ty * 4 + i;
        #pragma unroll
        for (int j = 0; j < 4; j++) {
            const int col = blockCol + tx * 4 + j;
            float v = acc[i][j] + bias[col];
            if (relu) v = fmaxf(v, 0.f);
            C[(size_t)row * N + col] = v;
        }
    }
}

// ---------------- attention: one block per (b, h, q). grid = (S, H, B), block = 256
__global__ __launch_bounds__(256) void attn_kernel(
        const float* __restrict__ q, const float* __restrict__ k,
        const float* __restrict__ v, const float* __restrict__ alibi,
        float* __restrict__ out) {
    const int qi = blockIdx.x;
    const int h  = blockIdx.y;
    const int b  = blockIdx.z;
    const int tid = threadIdx.x;

    __shared__ __align__(16) float qv[HD];
    __shared__ float sc[SS];
    __shared__ float red[64];
    __shared__ float pv[4][HD];

    const size_t rowbase = ((size_t)(b * SS + qi)) * DD + (size_t)h * HD;
    if (tid < HD) qv[tid] = q[rowbase + tid] * 0.125f;   // fold 1/sqrt(64)
    __syncthreads();

    const int nk = qi + 1;            // causal: keys 0..qi
    const float* al = alibi + ((size_t)h * SS + qi) * SS;

    float lmax = -1e30f;
    const float4* q4 = (const float4*)qv;
    for (int kk = tid; kk < nk; kk += 256) {
        const float4* k4 = (const float4*)&k[((size_t)(b * SS + kk)) * DD + (size_t)h * HD];
        float d = 0.f;
        #pragma unroll
        for (int j = 0; j < 16; j++) {
            float4 a = q4[j], bb = k4[j];
            d = fmaf(a.x, bb.x, d); d = fmaf(a.y, bb.y, d);
            d = fmaf(a.z, bb.z, d); d = fmaf(a.w, bb.w, d);
        }
        d += al[kk];
        sc[kk] = d;
        lmax = fmaxf(lmax, d);
    }
    const float gmax = block_max(lmax, red);

    float lsum = 0.f;
    for (int kk = tid; kk < nk; kk += 256) {
        float e = __expf(sc[kk] - gmax);
        sc[kk] = e;
        lsum += e;
    }
    const float gsum = block_sum(lsum, red);   // barriers also publish sc[]
    const float inv = 1.f / gsum;

    const int d = tid & 63;
    const int chunk = tid >> 6;      // 0..3
    float acc = 0.f;
    for (int kk = chunk; kk < nk; kk += 4)
        acc = fmaf(sc[kk], v[((size_t)(b * SS + kk)) * DD + (size_t)h * HD + d], acc);
    pv[chunk][d] = acc;
    __syncthreads();
    if (tid < HD)
        out[rowbase + tid] = (pv[0][tid] + pv[1][tid] + pv[2][tid] + pv[3][tid]) * inv;
}

// ---------------- residual add + layernorm: one block per row, 256 threads ----
__global__ __launch_bounds__(256) void ln_kernel(
        const float* __restrict__ a, const float* __restrict__ r,
        const float* __restrict__ g, const float* __restrict__ beta,
        float* __restrict__ out) {
    const int row = blockIdx.x;
    const int tid = threadIdx.x;
    __shared__ float red[64];

    float vals[3];
    float s = 0.f;
    #pragma unroll
    for (int i = 0; i < 3; i++) {
        const int col = i * 256 + tid;
        float t = a[(size_t)row * DD + col] + r[(size_t)row * DD + col];
        vals[i] = t;
        s += t;
    }
    const float mean = block_sum(s, red) * (1.f / DD);

    float s2 = 0.f;
    #pragma unroll
    for (int i = 0; i < 3; i++) {
        float d = vals[i] - mean;
        s2 += d * d;
    }
    const float var = block_sum(s2, red) * (1.f / DD);
    const float rstd = rsqrtf(var + LN_EPS);

    #pragma unroll
    for (int i = 0; i < 3; i++) {
        const int col = i * 256 + tid;
        out[(size_t)row * DD + col] = (vals[i] - mean) * rstd * g[col] + beta[col];
    }
}

extern "C" void kernel_launch(void* const* d_in, const int* in_sizes, int n_in,
                              void* d_out, int out_size, void* d_ws, size_t ws_size,
                              hipStream_t stream) {
    const float* x     = (const float*)d_in[0];
    const float* alibi = (const float*)d_in[1];
    const float* Wq = (const float*)d_in[2];
    const float* bq = (const float*)d_in[3];
    const float* Wk = (const float*)d_in[4];
    const float* bk = (const float*)d_in[5];
    const float* Wv = (const float*)d_in[6];
    const float* bv = (const float*)d_in[7];
    const float* Wo = (const float*)d_in[8];
    const float* bo = (const float*)d_in[9];
    const float* W1 = (const float*)d_in[10];
    const float* b1 = (const float*)d_in[11];
    const float* W2 = (const float*)d_in[12];
    const float* b2 = (const float*)d_in[13];
    const float* g1 = (const float*)d_in[14];
    const float* be1 = (const float*)d_in[15];
    const float* g2 = (const float*)d_in[16];
    const float* be2 = (const float*)d_in[17];
    float* out = (float*)d_out;

    float* ws   = (float*)d_ws;
    float* q    = ws;                          // 4096*768
    float* kbuf = q + (size_t)NROW * DD;       // 4096*768
    float* vbuf = kbuf + (size_t)NROW * DD;    // 4096*768
    float* attn = vbuf + (size_t)NROW * DD;    // 4096*768
    float* ff1  = attn + (size_t)NROW * DD;    // 4096*3072
    // reuse (all stream-ordered, producers complete before reuse):
    float* proj = q;     // attn @ Wo
    float* ln1  = kbuf;  // LN(x + proj)
    float* ff2  = vbuf;  // ff1 @ W2

    const dim3 blk(256);
    const dim3 gD(DD / 64, NROW / 64);     // (12, 64)
    const dim3 gFF(DFF / 64, NROW / 64);   // (48, 64)

    gemm_bias_kernel<<<gD, blk, 0, stream>>>(x, Wq, bq, q,    DD, DD, 0);
    gemm_bias_kernel<<<gD, blk, 0, stream>>>(x, Wk, bk, kbuf, DD, DD, 0);
    gemm_bias_kernel<<<gD, blk, 0, stream>>>(x, Wv, bv, vbuf, DD, DD, 0);

    attn_kernel<<<dim3(SS, HH, BB), blk, 0, stream>>>(q, kbuf, vbuf, alibi, attn);

    gemm_bias_kernel<<<gD, blk, 0, stream>>>(attn, Wo, bo, proj, DD, DD, 0);
    ln_kernel<<<dim3(NROW), blk, 0, stream>>>(x, proj, g1, be1, ln1);

    gemm_bias_kernel<<<gFF, blk, 0, stream>>>(ln1, W1, b1, ff1, DFF, DD, 1);
    gemm_bias_kernel<<<gD,  blk, 0, stream>>>(ff1, W2, b2, ff2, DD, DFF, 0);
    ln_kernel<<<dim3(NROW), blk, 0, stream>>>(ln1, ff2, g2, be2, out);
}

// Round 2
// 1282.303 us; speedup vs baseline: 3.6703x; 3.6703x over previous
//
#include <hip/hip_runtime.h>
#include <hip/hip_bf16.h>

#define BB 2
#define SS 2048
#define DD 768
#define HH 12
#define HD 64
#define DFF 3072
#define NROW (BB * SS)   // 4096
#define LN_EPS 1e-5f

typedef __attribute__((ext_vector_type(8))) short bf16x8;   // 8 bf16 in 4 VGPRs
typedef __attribute__((ext_vector_type(4))) float f32x4;

// ---------------- block-wide reductions (256 threads = 4 waves of 64) -------
__device__ __forceinline__ float block_sum(float v, float* red) {
    __syncthreads();
    #pragma unroll
    for (int off = 32; off > 0; off >>= 1) v += __shfl_down(v, off, 64);
    if ((threadIdx.x & 63) == 0) red[threadIdx.x >> 6] = v;
    __syncthreads();
    if (threadIdx.x == 0) red[0] = red[0] + red[1] + red[2] + red[3];
    __syncthreads();
    return red[0];
}

// ---------------- generic fp32 GEMM: C[4096 x N] = A[4096 x K] @ W[K x N] + bias
// grid = (N/64, 4096/64), block = 256. Optional ReLU, optional bf16 output w/ scale.
__global__ __launch_bounds__(256) void gemm_bias_kernel(
        const float* __restrict__ A, const float* __restrict__ W,
        const float* __restrict__ bias, float* __restrict__ Cf,
        __hip_bfloat16* __restrict__ Cb,
        int N, int K, int relu, int bf16out, float scale) {
    __shared__ float As[16][64];
    __shared__ float Bs[16][64];
    const int tid = threadIdx.x;
    const int tx = tid & 15;
    const int ty = tid >> 4;
    const int blockRow = blockIdx.y * 64;
    const int blockCol = blockIdx.x * 64;

    float acc[4][4] = {{0.f}};

    const int ar = tid >> 2;
    const int ac4 = (tid & 3) << 2;
    const int br = tid >> 4;
    const int bc4 = (tid & 15) << 2;

    for (int k0 = 0; k0 < K; k0 += 16) {
        float4 a = *(const float4*)&A[(size_t)(blockRow + ar) * K + k0 + ac4];
        As[ac4 + 0][ar] = a.x;
        As[ac4 + 1][ar] = a.y;
        As[ac4 + 2][ar] = a.z;
        As[ac4 + 3][ar] = a.w;
        *(float4*)&Bs[br][bc4] = *(const float4*)&W[(size_t)(k0 + br) * N + blockCol + bc4];
        __syncthreads();
        #pragma unroll
        for (int kk = 0; kk < 16; kk++) {
            float av[4], bv[4];
            #pragma unroll
            for (int i = 0; i < 4; i++) av[i] = As[kk][ty * 4 + i];
            #pragma unroll
            for (int j = 0; j < 4; j++) bv[j] = Bs[kk][tx * 4 + j];
            #pragma unroll
            for (int i = 0; i < 4; i++)
                #pragma unroll
                for (int j = 0; j < 4; j++)
                    acc[i][j] = fmaf(av[i], bv[j], acc[i][j]);
        }
        __syncthreads();
    }

    #pragma unroll
    for (int i = 0; i < 4; i++) {
        const int row = blockRow + ty * 4 + i;
        #pragma unroll
        for (int j = 0; j < 4; j++) {
            const int col = blockCol + tx * 4 + j;
            float v = acc[i][j] + bias[col];
            if (relu) v = fmaxf(v, 0.f);
            v *= scale;
            if (bf16out) Cb[(size_t)row * N + col] = __float2bfloat16(v);
            else         Cf[(size_t)row * N + col] = v;
        }
    }
}

// ---------------- MFMA flash attention -------------------------------------
// One wave (64 threads) per 16-row Q tile. grid = (S/16, H, B), block = 64.
// S^T = K·Q^T via mfma_f32_16x16x32_bf16 (C/D: col=lane&15=q, row=quad*4+reg=key)
// P -> LDS -> A-operand layout (A[m=lane&15][k=quad*8+j]) -> PV MFMA.
__global__ __launch_bounds__(64) void flash_attn_kernel(
        const __hip_bfloat16* __restrict__ Q, const __hip_bfloat16* __restrict__ K,
        const __hip_bfloat16* __restrict__ V, const float* __restrict__ alibi,
        float* __restrict__ out) {
    const int qt   = blockIdx.x;        // q tile (16 rows)
    const int h    = blockIdx.y;
    const int b    = blockIdx.z;
    const int lane = threadIdx.x;       // 0..63
    const int qq   = lane & 15;         // q-column index / fragment row index
    const int quad = lane >> 4;         // 0..3
    const int q0   = qt * 16;

    __shared__ float al_s[32 * 19];     // alibi tile [key_local][q_local], stride 19
    __shared__ float p_s[32 * 19];      // P tile [key_local][q_local], stride 19

    // Q fragments (B operand): lane holds col q = qq, k-dim = d = dbase + quad*8 + j
    const size_t qrow = ((size_t)(b * SS + q0 + qq)) * DD + (size_t)h * HD;
    bf16x8 qf0 = *(const bf16x8*)(Q + qrow + quad * 8);
    bf16x8 qf1 = *(const bf16x8*)(Q + qrow + 32 + quad * 8);

    f32x4 O[4] = {};                    // d0 = 0,16,32,48 ; C layout (row=q, col=d-sub)
    float m_i = -1e30f, l_i = 0.f;

    const float* alrow = alibi + ((size_t)h * SS + q0) * SS;
    const size_t kvbase = (size_t)(b * SS) * DD + (size_t)h * HD;

    for (int k0 = 0; k0 <= q0; k0 += 32) {
        // ---- stage alibi tile (rows q0..q0+15, cols k0..k0+31) transposed into LDS
        {
            const int r = lane >> 5;          // 0..1
            const int c = lane & 31;
            #pragma unroll
            for (int i = 0; i < 8; i++) {
                const int row = i * 2 + r;
                al_s[c * 19 + row] = alrow[(size_t)row * SS + k0 + c];
            }
        }
        __syncthreads();

        // ---- S^T = K · Q^T : two 16x16 chunks (keys k0+0..15, k0+16..31)
        f32x4 S[2] = {};
        #pragma unroll
        for (int c = 0; c < 2; c++) {
            const size_t krow = kvbase + (size_t)(k0 + c * 16 + qq) * DD;
            bf16x8 kf0 = *(const bf16x8*)(K + krow + quad * 8);
            bf16x8 kf1 = *(const bf16x8*)(K + krow + 32 + quad * 8);
            S[c] = __builtin_amdgcn_mfma_f32_16x16x32_bf16(kf0, qf0, S[c], 0, 0, 0);
            S[c] = __builtin_amdgcn_mfma_f32_16x16x32_bf16(kf1, qf1, S[c], 0, 0, 0);
        }

        // ---- alibi + causal mask, tile max per q-column
        float sv[8];
        float smax = -1e30f;
        #pragma unroll
        for (int c = 0; c < 2; c++) {
            #pragma unroll
            for (int r = 0; r < 4; r++) {
                const int kl = c * 16 + quad * 4 + r;
                float s = S[c][r] + al_s[kl * 19 + qq];
                if (k0 + kl > q0 + qq) s = -1e30f;   // causal
                sv[c * 4 + r] = s;
                smax = fmaxf(smax, s);
            }
        }
        smax = fmaxf(smax, __shfl_xor(smax, 16));
        smax = fmaxf(smax, __shfl_xor(smax, 32));

        const float nm = fmaxf(m_i, smax);
        const float alpha = __expf(m_i - nm);
        float lsum = 0.f;
        #pragma unroll
        for (int i = 0; i < 8; i++) {
            const float e = __expf(sv[i] - nm);
            sv[i] = e;
            lsum += e;
        }
        lsum += __shfl_xor(lsum, 16);
        lsum += __shfl_xor(lsum, 32);
        l_i = l_i * alpha + lsum;
        m_i = nm;

        // ---- rescale O rows by alpha (alpha lives per q-column -> shuffle to rows)
        #pragma unroll
        for (int r = 0; r < 4; r++) {
            const float ar = __shfl(alpha, quad * 4 + r);
            #pragma unroll
            for (int d = 0; d < 4; d++) O[d][r] *= ar;
        }

        // ---- P round-trip through LDS into A-operand layout
        #pragma unroll
        for (int c = 0; c < 2; c++) {
            #pragma unroll
            for (int r = 0; r < 4; r++) {
                const int kl = c * 16 + quad * 4 + r;
                p_s[kl * 19 + qq] = sv[c * 4 + r];
            }
        }
        __syncthreads();

        bf16x8 pf;
        #pragma unroll
        for (int j = 0; j < 8; j++) {
            const float v = p_s[(quad * 8 + j) * 19 + qq];
            const __hip_bfloat16 hb = __float2bfloat16(v);
            pf[j] = *(const short*)&hb;
        }

        // ---- PV: O[q][d] += P · V ; V B-fragment: col=d-sub=qq, k=key=quad*8+j
        const short* vp = (const short*)(V + kvbase + (size_t)(k0 + quad * 8) * DD) + qq;
        #pragma unroll
        for (int d0 = 0; d0 < 4; d0++) {
            bf16x8 vf;
            #pragma unroll
            for (int j = 0; j < 8; j++) vf[j] = vp[(size_t)j * DD + d0 * 16];
            O[d0] = __builtin_amdgcn_mfma_f32_16x16x32_bf16(pf, vf, O[d0], 0, 0, 0);
        }
        __syncthreads();   // protect al_s / p_s reuse next iteration
    }

    // ---- epilogue: divide by l (per q-column -> shuffle to rows), store fp32
    const float inv = 1.f / l_i;
    #pragma unroll
    for (int r = 0; r < 4; r++) {
        const float ir = __shfl(inv, quad * 4 + r);
        const int row = q0 + quad * 4 + r;
        float* op = out + (size_t)(b * SS + row) * DD + (size_t)h * HD + qq;
        op[0]  = O[0][r] * ir;
        op[16] = O[1][r] * ir;
        op[32] = O[2][r] * ir;
        op[48] = O[3][r] * ir;
    }
}

// ---------------- residual add + layernorm: one block per row, 256 threads ----
__global__ __launch_bounds__(256) void ln_kernel(
        const float* __restrict__ a, const float* __restrict__ r,
        const float* __restrict__ g, const float* __restrict__ beta,
        float* __restrict__ out) {
    const int row = blockIdx.x;
    const int tid = threadIdx.x;
    __shared__ float red[64];

    float vals[3];
    float s = 0.f;
    #pragma unroll
    for (int i = 0; i < 3; i++) {
        const int col = i * 256 + tid;
        float t = a[(size_t)row * DD + col] + r[(size_t)row * DD + col];
        vals[i] = t;
        s += t;
    }
    const float mean = block_sum(s, red) * (1.f / DD);

    float s2 = 0.f;
    #pragma unroll
    for (int i = 0; i < 3; i++) {
        float d = vals[i] - mean;
        s2 += d * d;
    }
    const float var = block_sum(s2, red) * (1.f / DD);
    const float rstd = rsqrtf(var + LN_EPS);

    #pragma unroll
    for (int i = 0; i < 3; i++) {
        const int col = i * 256 + tid;
        out[(size_t)row * DD + col] = (vals[i] - mean) * rstd * g[col] + beta[col];
    }
}

extern "C" void kernel_launch(void* const* d_in, const int* in_sizes, int n_in,
                              void* d_out, int out_size, void* d_ws, size_t ws_size,
                              hipStream_t stream) {
    const float* x     = (const float*)d_in[0];
    const float* alibi = (const float*)d_in[1];
    const float* Wq = (const float*)d_in[2];
    const float* bq = (const float*)d_in[3];
    const float* Wk = (const float*)d_in[4];
    const float* bk = (const float*)d_in[5];
    const float* Wv = (const float*)d_in[6];
    const float* bv = (const float*)d_in[7];
    const float* Wo = (const float*)d_in[8];
    const float* bo = (const float*)d_in[9];
    const float* W1 = (const float*)d_in[10];
    const float* b1 = (const float*)d_in[11];
    const float* W2 = (const float*)d_in[12];
    const float* b2 = (const float*)d_in[13];
    const float* g1 = (const float*)d_in[14];
    const float* be1 = (const float*)d_in[15];
    const float* g2 = (const float*)d_in[16];
    const float* be2 = (const float*)d_in[17];
    float* out = (float*)d_out;

    // workspace layout (94.4 MB total)
    __hip_bfloat16* qb = (__hip_bfloat16*)d_ws;
    __hip_bfloat16* kb = qb + (size_t)NROW * DD;
    __hip_bfloat16* vb = kb + (size_t)NROW * DD;
    float* attn = (float*)(vb + (size_t)NROW * DD);   // 12.6 MB
    float* ff1  = attn + (size_t)NROW * DD;           // 50.3 MB
    float* proj = ff1 + (size_t)NROW * DFF;           // 12.6 MB
    float* ln1  = attn;   // reuse: attn consumed by Wo GEMM before ln writes
    float* ff2  = proj;   // reuse: proj consumed by first ln before ff2 written

    const dim3 blk(256);
    const dim3 gD(DD / 64, NROW / 64);
    const dim3 gFF(DFF / 64, NROW / 64);
    const float qscale = 0.125f;   // 1/sqrt(HD), folded into q

    gemm_bias_kernel<<<gD, blk, 0, stream>>>(x, Wq, bq, nullptr, qb, DD, DD, 0, 1, qscale);
    gemm_bias_kernel<<<gD, blk, 0, stream>>>(x, Wk, bk, nullptr, kb, DD, DD, 0, 1, 1.f);
    gemm_bias_kernel<<<gD, blk, 0, stream>>>(x, Wv, bv, nullptr, vb, DD, DD, 0, 1, 1.f);

    flash_attn_kernel<<<dim3(SS / 16, HH, BB), dim3(64), 0, stream>>>(qb, kb, vb, alibi, attn);

    gemm_bias_kernel<<<gD, blk, 0, stream>>>(attn, Wo, bo, proj, nullptr, DD, DD, 0, 0, 1.f);
    ln_kernel<<<dim3(NROW), blk, 0, stream>>>(x, proj, g1, be1, ln1);

    gemm_bias_kernel<<<gFF, blk, 0, stream>>>(ln1, W1, b1, ff1, nullptr, DFF, DD, 1, 0, 1.f);
    gemm_bias_kernel<<<gD,  blk, 0, stream>>>(ff1, W2, b2, ff2, nullptr, DD, DFF, 0, 0, 1.f);
    ln_kernel<<<dim3(NROW), blk, 0, stream>>>(ln1, ff2, g2, be2, out);
}

// Round 3
// 637.320 us; speedup vs baseline: 7.3848x; 2.0120x over previous
//
#include <hip/hip_runtime.h>
#include <hip/hip_bf16.h>

#define BB 2
#define SS 2048
#define DD 768
#define HH 12
#define HD 64
#define DFF 3072
#define NROW (BB * SS)   // 4096
#define QLD  2304        // fused QKV row stride
#define LN_EPS 1e-5f

typedef __attribute__((ext_vector_type(8))) short bf16x8;   // 8 bf16 in 4 VGPRs
typedef __attribute__((ext_vector_type(4))) float f32x4;

__device__ __forceinline__ void gll16(const void* g, void* l) {
    __builtin_amdgcn_global_load_lds(
        (const __attribute__((address_space(1))) unsigned int*)g,
        (__attribute__((address_space(3))) unsigned int*)l,
        16, 0, 0);
}

__device__ __forceinline__ unsigned short bf16bits(float f) {
    __hip_bfloat16 h = __float2bfloat16(f);
    return *(unsigned short*)&h;
}

// ---------------- block-wide reductions (256 threads = 4 waves of 64) -------
__device__ __forceinline__ float block_sum(float v, float* red) {
    __syncthreads();
    #pragma unroll
    for (int off = 32; off > 0; off >>= 1) v += __shfl_down(v, off, 64);
    if ((threadIdx.x & 63) == 0) red[threadIdx.x >> 6] = v;
    __syncthreads();
    if (threadIdx.x == 0) red[0] = red[0] + red[1] + red[2] + red[3];
    __syncthreads();
    return red[0];
}

// ---------------- bf16 MFMA GEMM (m97 structure) ----------------------------
// C[M x N] = A[M x K](bf16) @ BT[N x K](bf16)^T + bias. 256 thr = 4 waves (2x2),
// each wave (TM/2 x TN/2) via 16x16x32 MFMAs. global_load_lds width-16 staging.
template<int TM, int TN>
__global__ __launch_bounds__(256) void mfma_gemm(
        const __hip_bfloat16* __restrict__ A, const __hip_bfloat16* __restrict__ BT,
        const float* __restrict__ bias, float* __restrict__ Cf,
        __hip_bfloat16* __restrict__ Cb,
        int N, int K, int relu, int bf16out, int qscale_cols) {
    constexpr int BK = 32;
    constexpr int MW = TM / 32;   // 16-tiles per wave (m)
    constexpr int NW = TN / 32;   // 16-tiles per wave (n)
    __shared__ __hip_bfloat16 a_s[TM * BK];   // [m][k], 64B rows, lane-order contiguous
    __shared__ __hip_bfloat16 b_s[TN * BK];   // [n][k]

    const int tid  = threadIdx.x;
    const int lane = tid & 63;
    const int wid  = tid >> 6;
    const int wm   = (wid & 1) * (TM / 2);
    const int wn   = (wid >> 1) * (TN / 2);
    const int qq   = lane & 15;
    const int quad = lane >> 4;
    const int m0 = blockIdx.y * TM;
    const int n0 = blockIdx.x * TN;

    const int srow = lane >> 2;          // 0..15 within wave's 16-row chunk
    const int scol = (lane & 3) * 8;     // bf16 elems (16 B)

    f32x4 acc[MW][NW] = {};

    for (int k0 = 0; k0 < K; k0 += BK) {
        const __hip_bfloat16* Ag = A + (size_t)m0 * K + k0 + scol;
        #pragma unroll
        for (int i = 0; i < TM / 64; i++) {
            const int row = i * 64 + wid * 16 + srow;
            gll16(Ag + (size_t)row * K, a_s + row * BK + scol);
        }
        const __hip_bfloat16* Bg = BT + (size_t)n0 * K + k0 + scol;
        #pragma unroll
        for (int i = 0; i < TN / 64; i++) {
            const int row = i * 64 + wid * 16 + srow;
            gll16(Bg + (size_t)row * K, b_s + row * BK + scol);
        }
        __syncthreads();

        bf16x8 af[MW], bfr[NW];
        #pragma unroll
        for (int mi = 0; mi < MW; mi++)
            af[mi] = *(const bf16x8*)(a_s + (wm + mi * 16 + qq) * BK + quad * 8);
        #pragma unroll
        for (int ni = 0; ni < NW; ni++)
            bfr[ni] = *(const bf16x8*)(b_s + (wn + ni * 16 + qq) * BK + quad * 8);
        #pragma unroll
        for (int mi = 0; mi < MW; mi++)
            #pragma unroll
            for (int ni = 0; ni < NW; ni++)
                acc[mi][ni] = __builtin_amdgcn_mfma_f32_16x16x32_bf16(
                        af[mi], bfr[ni], acc[mi][ni], 0, 0, 0);
        __syncthreads();
    }

    // epilogue: C/D layout col=lane&15, row=quad*4+reg
    #pragma unroll
    for (int mi = 0; mi < MW; mi++) {
        #pragma unroll
        for (int ni = 0; ni < NW; ni++) {
            const int col = n0 + wn + ni * 16 + qq;
            const float bv = bias[col];
            const float sc = (col < qscale_cols) ? 0.125f : 1.0f;
            #pragma unroll
            for (int r = 0; r < 4; r++) {
                const int row = m0 + wm + mi * 16 + quad * 4 + r;
                float v = acc[mi][ni][r] + bv;
                if (relu) v = fmaxf(v, 0.f);
                v *= sc;
                if (bf16out) Cb[(size_t)row * N + col] = __float2bfloat16(v);
                else         Cf[(size_t)row * N + col] = v;
            }
        }
    }
}

// ---------------- weight transpose + bf16 convert: out[n][k] = in[k][n] -----
__global__ __launch_bounds__(256) void transpose_bf16_kernel(
        const float* __restrict__ in, __hip_bfloat16* __restrict__ out,
        int K, int N) {
    __shared__ float t[32][33];
    const int n0 = blockIdx.x * 32;
    const int k0 = blockIdx.y * 32;
    const int r = threadIdx.x >> 3;      // 0..31
    const int c = threadIdx.x & 7;       // 0..7
    float4 v = *(const float4*)&in[(size_t)(k0 + r) * N + n0 + c * 4];
    t[r][c * 4 + 0] = v.x;
    t[r][c * 4 + 1] = v.y;
    t[r][c * 4 + 2] = v.z;
    t[r][c * 4 + 3] = v.w;
    __syncthreads();
    union { unsigned short u[4]; uint2 w; } pk;
    #pragma unroll
    for (int j = 0; j < 4; j++) pk.u[j] = bf16bits(t[c * 4 + j][r]);
    *(uint2*)&out[(size_t)(n0 + r) * K + k0 + c * 4] = pk.w;
}

// ---------------- fp32 -> bf16 convert (x) ----------------------------------
__global__ __launch_bounds__(256) void cvt_bf16_kernel(
        const float* __restrict__ in, __hip_bfloat16* __restrict__ out) {
    const int i = blockIdx.x * 256 + threadIdx.x;
    float4 v = ((const float4*)in)[i];
    union { unsigned short u[4]; uint2 w; } pk;
    pk.u[0] = bf16bits(v.x); pk.u[1] = bf16bits(v.y);
    pk.u[2] = bf16bits(v.z); pk.u[3] = bf16bits(v.w);
    ((uint2*)out)[i] = pk.w;
}

// ---------------- concat q/k/v biases ---------------------------------------
__global__ __launch_bounds__(256) void concat_bias_kernel(
        const float* __restrict__ bq, const float* __restrict__ bk,
        const float* __restrict__ bv, float* __restrict__ o) {
    const int i = blockIdx.x * 256 + threadIdx.x;
    if (i < QLD)
        o[i] = (i < DD) ? bq[i] : ((i < 2 * DD) ? bk[i - DD] : bv[i - 2 * DD]);
}

// ---------------- MFMA flash attention (qkv fused input, bf16 out) ----------
__global__ __launch_bounds__(64) void flash_attn_kernel(
        const __hip_bfloat16* __restrict__ QKV, const float* __restrict__ alibi,
        __hip_bfloat16* __restrict__ outb) {
    const int qt   = blockIdx.x;
    const int h    = blockIdx.y;
    const int b    = blockIdx.z;
    const int lane = threadIdx.x;
    const int qq   = lane & 15;
    const int quad = lane >> 4;
    const int q0   = qt * 16;

    __shared__ float al_s[32 * 19];
    __shared__ float p_s[32 * 19];

    const size_t qrow = ((size_t)(b * SS + q0 + qq)) * QLD + (size_t)h * HD;
    bf16x8 qf0 = *(const bf16x8*)(QKV + qrow + quad * 8);
    bf16x8 qf1 = *(const bf16x8*)(QKV + qrow + 32 + quad * 8);

    f32x4 O[4] = {};
    float m_i = -1e30f, l_i = 0.f;

    const float* alrow = alibi + ((size_t)h * SS + q0) * SS;
    const size_t kbase = (size_t)(b * SS) * QLD + DD + (size_t)h * HD;
    const size_t vbase = (size_t)(b * SS) * QLD + 2 * DD + (size_t)h * HD;

    for (int k0 = 0; k0 <= q0; k0 += 32) {
        {
            const int r = lane >> 5;
            const int c = lane & 31;
            #pragma unroll
            for (int i = 0; i < 8; i++) {
                const int row = i * 2 + r;
                al_s[c * 19 + row] = alrow[(size_t)row * SS + k0 + c];
            }
        }
        __syncthreads();

        f32x4 S[2] = {};
        #pragma unroll
        for (int c = 0; c < 2; c++) {
            const size_t krow = kbase + (size_t)(k0 + c * 16 + qq) * QLD;
            bf16x8 kf0 = *(const bf16x8*)(QKV + krow + quad * 8);
            bf16x8 kf1 = *(const bf16x8*)(QKV + krow + 32 + quad * 8);
            S[c] = __builtin_amdgcn_mfma_f32_16x16x32_bf16(kf0, qf0, S[c], 0, 0, 0);
            S[c] = __builtin_amdgcn_mfma_f32_16x16x32_bf16(kf1, qf1, S[c], 0, 0, 0);
        }

        float sv[8];
        float smax = -1e30f;
        #pragma unroll
        for (int c = 0; c < 2; c++) {
            #pragma unroll
            for (int r = 0; r < 4; r++) {
                const int kl = c * 16 + quad * 4 + r;
                float s = S[c][r] + al_s[kl * 19 + qq];
                if (k0 + kl > q0 + qq) s = -1e30f;
                sv[c * 4 + r] = s;
                smax = fmaxf(smax, s);
            }
        }
        smax = fmaxf(smax, __shfl_xor(smax, 16));
        smax = fmaxf(smax, __shfl_xor(smax, 32));

        const float nm = fmaxf(m_i, smax);
        const float alpha = __expf(m_i - nm);
        float lsum = 0.f;
        #pragma unroll
        for (int i = 0; i < 8; i++) {
            const float e = __expf(sv[i] - nm);
            sv[i] = e;
            lsum += e;
        }
        lsum += __shfl_xor(lsum, 16);
        lsum += __shfl_xor(lsum, 32);
        l_i = l_i * alpha + lsum;
        m_i = nm;

        #pragma unroll
        for (int r = 0; r < 4; r++) {
            const float ar = __shfl(alpha, quad * 4 + r);
            #pragma unroll
            for (int d = 0; d < 4; d++) O[d][r] *= ar;
        }

        #pragma unroll
        for (int c = 0; c < 2; c++)
            #pragma unroll
            for (int r = 0; r < 4; r++)
                p_s[(c * 16 + quad * 4 + r) * 19 + qq] = sv[c * 4 + r];
        __syncthreads();

        bf16x8 pf;
        #pragma unroll
        for (int j = 0; j < 8; j++)
            pf[j] = (short)bf16bits(p_s[(quad * 8 + j) * 19 + qq]);

        const short* vp = (const short*)(QKV + vbase + (size_t)(k0 + quad * 8) * QLD) + qq;
        #pragma unroll
        for (int d0 = 0; d0 < 4; d0++) {
            bf16x8 vf;
            #pragma unroll
            for (int j = 0; j < 8; j++) vf[j] = vp[(size_t)j * QLD + d0 * 16];
            O[d0] = __builtin_amdgcn_mfma_f32_16x16x32_bf16(pf, vf, O[d0], 0, 0, 0);
        }
        __syncthreads();
    }

    const float inv = 1.f / l_i;
    #pragma unroll
    for (int r = 0; r < 4; r++) {
        const float ir = __shfl(inv, quad * 4 + r);
        const int row = q0 + quad * 4 + r;
        __hip_bfloat16* op = outb + (size_t)(b * SS + row) * DD + (size_t)h * HD + qq;
        op[0]  = __float2bfloat16(O[0][r] * ir);
        op[16] = __float2bfloat16(O[1][r] * ir);
        op[32] = __float2bfloat16(O[2][r] * ir);
        op[48] = __float2bfloat16(O[3][r] * ir);
    }
}

// ---------------- residual add + layernorm (fp32 out + optional bf16 out) ---
__global__ __launch_bounds__(256) void ln_kernel(
        const float* __restrict__ a, const float* __restrict__ r,
        const float* __restrict__ g, const float* __restrict__ beta,
        float* __restrict__ outf, __hip_bfloat16* __restrict__ outb) {
    const int row = blockIdx.x;
    const int tid = threadIdx.x;
    __shared__ float red[64];

    float vals[3];
    float s = 0.f;
    #pragma unroll
    for (int i = 0; i < 3; i++) {
        const int col = i * 256 + tid;
        float t = a[(size_t)row * DD + col] + r[(size_t)row * DD + col];
        vals[i] = t;
        s += t;
    }
    const float mean = block_sum(s, red) * (1.f / DD);

    float s2 = 0.f;
    #pragma unroll
    for (int i = 0; i < 3; i++) {
        float d = vals[i] - mean;
        s2 += d * d;
    }
    const float var = block_sum(s2, red) * (1.f / DD);
    const float rstd = rsqrtf(var + LN_EPS);

    #pragma unroll
    for (int i = 0; i < 3; i++) {
        const int col = i * 256 + tid;
        const float o = (vals[i] - mean) * rstd * g[col] + beta[col];
        outf[(size_t)row * DD + col] = o;
        if (outb) outb[(size_t)row * DD + col] = __float2bfloat16(o);
    }
}

extern "C" void kernel_launch(void* const* d_in, const int* in_sizes, int n_in,
                              void* d_out, int out_size, void* d_ws, size_t ws_size,
                              hipStream_t stream) {
    const float* x     = (const float*)d_in[0];
    const float* alibi = (const float*)d_in[1];
    const float* Wq = (const float*)d_in[2];
    const float* bq = (const float*)d_in[3];
    const float* Wk = (const float*)d_in[4];
    const float* bk = (const float*)d_in[5];
    const float* Wv = (const float*)d_in[6];
    const float* bv = (const float*)d_in[7];
    const float* Wo = (const float*)d_in[8];
    const float* bo = (const float*)d_in[9];
    const float* W1 = (const float*)d_in[10];
    const float* b1 = (const float*)d_in[11];
    const float* W2 = (const float*)d_in[12];
    const float* b2 = (const float*)d_in[13];
    const float* g1 = (const float*)d_in[14];
    const float* be1 = (const float*)d_in[15];
    const float* g2 = (const float*)d_in[16];
    const float* be2 = (const float*)d_in[17];
    float* out = (float*)d_out;

    // ---- workspace layout (~77 MB) ----
    char* p = (char*)d_ws;
    auto alloc = [&](size_t bytes) { char* r = p; p += (bytes + 255) & ~(size_t)255; return r; };
    __hip_bfloat16* WqkvT = (__hip_bfloat16*)alloc((size_t)QLD * DD * 2);
    __hip_bfloat16* WoT   = (__hip_bfloat16*)alloc((size_t)DD * DD * 2);
    __hip_bfloat16* W1T   = (__hip_bfloat16*)alloc((size_t)DFF * DD * 2);
    __hip_bfloat16* W2T   = (__hip_bfloat16*)alloc((size_t)DD * DFF * 2);
    float*          biasc = (float*)alloc((size_t)QLD * 4);
    __hip_bfloat16* xb    = (__hip_bfloat16*)alloc((size_t)NROW * DD * 2);   // later: ln1b
    __hip_bfloat16* qkvb  = (__hip_bfloat16*)alloc((size_t)NROW * DFF * 2);  // later: ff1b
    __hip_bfloat16* attnb = (__hip_bfloat16*)alloc((size_t)NROW * DD * 2);
    float*          proj  = (float*)alloc((size_t)NROW * DD * 4);            // later: ff2
    float*          ln1   = (float*)alloc((size_t)NROW * DD * 4);
    __hip_bfloat16* ln1b  = xb;
    __hip_bfloat16* ff1b  = qkvb;
    float*          ff2   = proj;

    const dim3 blk(256);

    // ---- prep: weight transposes (fp32 -> bf16, K-major), bias concat, x ----
    transpose_bf16_kernel<<<dim3(DD / 32, DD / 32), blk, 0, stream>>>(Wq, WqkvT, DD, DD);
    transpose_bf16_kernel<<<dim3(DD / 32, DD / 32), blk, 0, stream>>>(Wk, WqkvT + (size_t)DD * DD, DD, DD);
    transpose_bf16_kernel<<<dim3(DD / 32, DD / 32), blk, 0, stream>>>(Wv, WqkvT + (size_t)2 * DD * DD, DD, DD);
    transpose_bf16_kernel<<<dim3(DD / 32, DD / 32), blk, 0, stream>>>(Wo, WoT, DD, DD);
    transpose_bf16_kernel<<<dim3(DFF / 32, DD / 32), blk, 0, stream>>>(W1, W1T, DD, DFF);
    transpose_bf16_kernel<<<dim3(DD / 32, DFF / 32), blk, 0, stream>>>(W2, W2T, DFF, DD);
    concat_bias_kernel<<<dim3((QLD + 255) / 256), blk, 0, stream>>>(bq, bk, bv, biasc);
    cvt_bf16_kernel<<<dim3(NROW * DD / 4 / 256), blk, 0, stream>>>(x, xb);

    // ---- fused QKV projection: [4096x768] @ [768x2304] -> bf16, q scaled ----
    mfma_gemm<128, 128><<<dim3(QLD / 128, NROW / 128), blk, 0, stream>>>(
            xb, WqkvT, biasc, nullptr, qkvb, QLD, DD, 0, 1, DD);

    flash_attn_kernel<<<dim3(SS / 16, HH, BB), dim3(64), 0, stream>>>(qkvb, alibi, attnb);

    // ---- output projection -> fp32 ----
    mfma_gemm<128, 64><<<dim3(DD / 64, NROW / 128), blk, 0, stream>>>(
            attnb, WoT, bo, proj, nullptr, DD, DD, 0, 0, 0);

    ln_kernel<<<dim3(NROW), blk, 0, stream>>>(x, proj, g1, be1, ln1, ln1b);

    // ---- FFN ----
    mfma_gemm<128, 128><<<dim3(DFF / 128, NROW / 128), blk, 0, stream>>>(
            ln1b, W1T, b1, nullptr, ff1b, DFF, DD, 1, 1, 0);
    mfma_gemm<128, 64><<<dim3(DD / 64, NROW / 128), blk, 0, stream>>>(
            ff1b, W2T, b2, ff2, nullptr, DD, DFF, 0, 0, 0);

    ln_kernel<<<dim3(NROW), blk, 0, stream>>>(ln1, ff2, g2, be2, out, nullptr);
}

// Round 5
// 571.476 us; speedup vs baseline: 8.2357x; 1.1152x over previous
//
#include <hip/hip_runtime.h>
#include <hip/hip_bf16.h>

#define BB 2
#define SS 2048
#define DD 768
#define HH 12
#define HD 64
#define DFF 3072
#define NROW (BB * SS)   // 4096
#define QLD  2304        // fused QKV row stride
#define LN_EPS 1e-5f

typedef __attribute__((ext_vector_type(8))) short bf16x8;   // 8 bf16 in 4 VGPRs
typedef __attribute__((ext_vector_type(4))) short bf16x4;
typedef __attribute__((ext_vector_type(4))) float f32x4;

__device__ __forceinline__ void gll16(const void* g, void* l) {
    __builtin_amdgcn_global_load_lds(
        (const __attribute__((address_space(1))) unsigned int*)g,
        (__attribute__((address_space(3))) unsigned int*)l,
        16, 0, 0);
}

__device__ __forceinline__ unsigned short bf16bits(float f) {
    __hip_bfloat16 h = __float2bfloat16(f);
    return *(unsigned short*)&h;
}

__device__ __forceinline__ float bf16tof(unsigned short u) {
    unsigned int ui = ((unsigned int)u) << 16;
    return __uint_as_float(ui);
}

// ---------------- block-wide reductions (256 threads = 4 waves of 64) -------
__device__ __forceinline__ float block_sum(float v, float* red) {
    __syncthreads();
    #pragma unroll
    for (int off = 32; off > 0; off >>= 1) v += __shfl_down(v, off, 64);
    if ((threadIdx.x & 63) == 0) red[threadIdx.x >> 6] = v;
    __syncthreads();
    if (threadIdx.x == 0) red[0] = red[0] + red[1] + red[2] + red[3];
    __syncthreads();
    return red[0];
}

// ---------------- bf16 MFMA GEMM (m97 structure) ----------------------------
template<int TM, int TN>
__global__ __launch_bounds__(256) void mfma_gemm(
        const __hip_bfloat16* __restrict__ A, const __hip_bfloat16* __restrict__ BT,
        const float* __restrict__ bias, float* __restrict__ Cf,
        __hip_bfloat16* __restrict__ Cb,
        int N, int K, int relu, int bf16out, int qscale_cols) {
    constexpr int BK = 32;
    constexpr int MW = TM / 32;
    constexpr int NW = TN / 32;
    __shared__ __hip_bfloat16 a_s[TM * BK];
    __shared__ __hip_bfloat16 b_s[TN * BK];

    const int tid  = threadIdx.x;
    const int lane = tid & 63;
    const int wid  = tid >> 6;
    const int wm   = (wid & 1) * (TM / 2);
    const int wn   = (wid >> 1) * (TN / 2);
    const int qq   = lane & 15;
    const int quad = lane >> 4;
    const int m0 = blockIdx.y * TM;
    const int n0 = blockIdx.x * TN;

    const int srow = lane >> 2;
    const int scol = (lane & 3) * 8;

    f32x4 acc[MW][NW] = {};

    for (int k0 = 0; k0 < K; k0 += BK) {
        const __hip_bfloat16* Ag = A + (size_t)m0 * K + k0 + scol;
        #pragma unroll
        for (int i = 0; i < TM / 64; i++) {
            const int row = i * 64 + wid * 16 + srow;
            gll16(Ag + (size_t)row * K, a_s + row * BK + scol);
        }
        const __hip_bfloat16* Bg = BT + (size_t)n0 * K + k0 + scol;
        #pragma unroll
        for (int i = 0; i < TN / 64; i++) {
            const int row = i * 64 + wid * 16 + srow;
            gll16(Bg + (size_t)row * K, b_s + row * BK + scol);
        }
        __syncthreads();

        bf16x8 af[MW], bfr[NW];
        #pragma unroll
        for (int mi = 0; mi < MW; mi++)
            af[mi] = *(const bf16x8*)(a_s + (wm + mi * 16 + qq) * BK + quad * 8);
        #pragma unroll
        for (int ni = 0; ni < NW; ni++)
            bfr[ni] = *(const bf16x8*)(b_s + (wn + ni * 16 + qq) * BK + quad * 8);
        #pragma unroll
        for (int mi = 0; mi < MW; mi++)
            #pragma unroll
            for (int ni = 0; ni < NW; ni++)
                acc[mi][ni] = __builtin_amdgcn_mfma_f32_16x16x32_bf16(
                        af[mi], bfr[ni], acc[mi][ni], 0, 0, 0);
        __syncthreads();
    }

    #pragma unroll
    for (int mi = 0; mi < MW; mi++) {
        #pragma unroll
        for (int ni = 0; ni < NW; ni++) {
            const int col = n0 + wn + ni * 16 + qq;
            const float bv = bias[col];
            const float sc = (col < qscale_cols) ? 0.125f : 1.0f;
            #pragma unroll
            for (int r = 0; r < 4; r++) {
                const int row = m0 + wm + mi * 16 + quad * 4 + r;
                float v = acc[mi][ni][r] + bv;
                if (relu) v = fmaxf(v, 0.f);
                v *= sc;
                if (bf16out) Cb[(size_t)row * N + col] = __float2bfloat16(v);
                else         Cf[(size_t)row * N + col] = v;
            }
        }
    }
}

// ---------------- weight transpose + bf16 convert ---------------------------
__global__ __launch_bounds__(256) void transpose_bf16_kernel(
        const float* __restrict__ in, __hip_bfloat16* __restrict__ out,
        int K, int N) {
    __shared__ float t[32][33];
    const int n0 = blockIdx.x * 32;
    const int k0 = blockIdx.y * 32;
    const int r = threadIdx.x >> 3;
    const int c = threadIdx.x & 7;
    float4 v = *(const float4*)&in[(size_t)(k0 + r) * N + n0 + c * 4];
    t[r][c * 4 + 0] = v.x;
    t[r][c * 4 + 1] = v.y;
    t[r][c * 4 + 2] = v.z;
    t[r][c * 4 + 3] = v.w;
    __syncthreads();
    union { unsigned short u[4]; uint2 w; } pk;
    #pragma unroll
    for (int j = 0; j < 4; j++) pk.u[j] = bf16bits(t[c * 4 + j][r]);
    *(uint2*)&out[(size_t)(n0 + r) * K + k0 + c * 4] = pk.w;
}

__global__ __launch_bounds__(256) void cvt_bf16_kernel(
        const float* __restrict__ in, __hip_bfloat16* __restrict__ out) {
    const int i = blockIdx.x * 256 + threadIdx.x;
    float4 v = ((const float4*)in)[i];
    union { unsigned short u[4]; uint2 w; } pk;
    pk.u[0] = bf16bits(v.x); pk.u[1] = bf16bits(v.y);
    pk.u[2] = bf16bits(v.z); pk.u[3] = bf16bits(v.w);
    ((uint2*)out)[i] = pk.w;
}

__global__ __launch_bounds__(256) void concat_bias_kernel(
        const float* __restrict__ bq, const float* __restrict__ bk,
        const float* __restrict__ bv, float* __restrict__ o) {
    const int i = blockIdx.x * 256 + threadIdx.x;
    if (i < QLD)
        o[i] = (i < DD) ? bq[i] : ((i < 2 * DD) ? bk[i - DD] : bv[i - 2 * DD]);
}

// ---------------- MFMA flash attention v2 -----------------------------------
// Block = 256 thr (4 waves), 64-row Q tile (wave w: rows q0+w*16..+15), 64-key
// K-steps. K/V/alibi staged in LDS (stride 72 bf16 -> conflict-free b128 frags).
// S^T = K.Q^T (C: row=key, col=q); softmax in-lane; P via per-wave LDS tile.
__global__ __launch_bounds__(256) void flash_attn_kernel(
        const __hip_bfloat16* __restrict__ QKV, const float* __restrict__ alibi,
        __hip_bfloat16* __restrict__ outb) {
    const int qt = (int)gridDim.x - 1 - (int)blockIdx.x;   // heavy blocks first
    const int h  = blockIdx.y;
    const int b  = blockIdx.z;
    const int tid  = threadIdx.x;
    const int lane = tid & 63;
    const int w    = tid >> 6;
    const int qq   = lane & 15;
    const int quad = lane >> 4;
    const int q0   = qt * 64;

    __shared__ unsigned short K_s[64 * 72];   // [key][d]
    __shared__ unsigned short V_t[64 * 72];   // [d][key]
    __shared__ unsigned short al_q[64 * 72];  // [q_local][key] (bf16)
    __shared__ unsigned short P_t[4][16 * 72];// per-wave [q_local16][key]

    // Q fragments (B operand), per wave: rows q0 + w*16 + qq
    const size_t qrow = ((size_t)(b * SS + q0 + w * 16 + qq)) * QLD + (size_t)h * HD;
    const bf16x8 qf0 = *(const bf16x8*)(QKV + qrow + quad * 8);
    const bf16x8 qf1 = *(const bf16x8*)(QKV + qrow + 32 + quad * 8);

    f32x4 O[4] = {};
    float m_i = -1e30f, l_i = 0.f;

    const float* alrow = alibi + ((size_t)h * SS + q0) * SS;   // rows q0..q0+63
    const size_t kvrow0 = (size_t)(b * SS) * QLD + (size_t)h * HD + w * 16;
    const int lim = q0 + w * 16 + qq;    // key valid iff k0+key <= lim

    for (int k0 = 0; k0 <= q0; k0 += 64) {
        __syncthreads();   // previous iteration's LDS reads complete

        // ---- cooperative staging: thread (w, lane): key/q-row = lane, chunk = w*16
        {
            const size_t kv = kvrow0 + (size_t)(k0 + lane) * QLD;
            bf16x8 kv0 = *(const bf16x8*)(QKV + DD + kv);
            bf16x8 kv1 = *(const bf16x8*)(QKV + DD + kv + 8);
            *(bf16x8*)&K_s[lane * 72 + w * 16]     = kv0;
            *(bf16x8*)&K_s[lane * 72 + w * 16 + 8] = kv1;
            bf16x8 vv0 = *(const bf16x8*)(QKV + 2 * DD + kv);
            bf16x8 vv1 = *(const bf16x8*)(QKV + 2 * DD + kv + 8);
            #pragma unroll
            for (int j = 0; j < 8; j++) {
                V_t[(w * 16 + j) * 72 + lane]     = vv0[j];
                V_t[(w * 16 + 8 + j) * 72 + lane] = vv1[j];
            }
            const float* ap = alrow + (size_t)lane * SS + k0 + w * 16;
            union { unsigned short u[8]; bf16x8 v; } pa0, pa1;
            float4 f0 = *(const float4*)(ap);
            float4 f1 = *(const float4*)(ap + 4);
            float4 f2 = *(const float4*)(ap + 8);
            float4 f3 = *(const float4*)(ap + 12);
            pa0.u[0] = bf16bits(f0.x); pa0.u[1] = bf16bits(f0.y);
            pa0.u[2] = bf16bits(f0.z); pa0.u[3] = bf16bits(f0.w);
            pa0.u[4] = bf16bits(f1.x); pa0.u[5] = bf16bits(f1.y);
            pa0.u[6] = bf16bits(f1.z); pa0.u[7] = bf16bits(f1.w);
            pa1.u[0] = bf16bits(f2.x); pa1.u[1] = bf16bits(f2.y);
            pa1.u[2] = bf16bits(f2.z); pa1.u[3] = bf16bits(f2.w);
            pa1.u[4] = bf16bits(f3.x); pa1.u[5] = bf16bits(f3.y);
            pa1.u[6] = bf16bits(f3.z); pa1.u[7] = bf16bits(f3.w);
            *(bf16x8*)&al_q[lane * 72 + w * 16]     = pa0.v;
            *(bf16x8*)&al_q[lane * 72 + w * 16 + 8] = pa1.v;
        }
        __syncthreads();

        // ---- S^T = K.Q^T : 4 key-chunks of 16
        f32x4 S[4];
        #pragma unroll
        for (int c = 0; c < 4; c++) {
            f32x4 s = {};
            bf16x8 kf0 = *(const bf16x8*)&K_s[(c * 16 + qq) * 72 + quad * 8];
            bf16x8 kf1 = *(const bf16x8*)&K_s[(c * 16 + qq) * 72 + 32 + quad * 8];
            s = __builtin_amdgcn_mfma_f32_16x16x32_bf16(kf0, qf0, s, 0, 0, 0);
            s = __builtin_amdgcn_mfma_f32_16x16x32_bf16(kf1, qf1, s, 0, 0, 0);
            S[c] = s;
        }

        // ---- scores: + alibi (row w*16+qq of block tile!), causal mask
        float sv[16];
        float smax = -1e30f;
        const int klim = lim - k0;
        #pragma unroll
        for (int c = 0; c < 4; c++) {
            bf16x4 a4 = *(const bf16x4*)&al_q[(w * 16 + qq) * 72 + c * 16 + quad * 4];
            #pragma unroll
            for (int r = 0; r < 4; r++) {
                const int key = c * 16 + quad * 4 + r;
                float s = S[c][r] + bf16tof((unsigned short)a4[r]);
                if (key > klim) s = -1e30f;
                sv[c * 4 + r] = s;
                smax = fmaxf(smax, s);
            }
        }
        smax = fmaxf(smax, __shfl_xor(smax, 16));
        smax = fmaxf(smax, __shfl_xor(smax, 32));

        const float nm = fmaxf(m_i, smax);
        const float alpha = __expf(m_i - nm);
        float lsum = 0.f;
        #pragma unroll
        for (int i = 0; i < 16; i++) {
            const float e = __expf(sv[i] - nm);
            sv[i] = e;
            lsum += e;
        }
        lsum += __shfl_xor(lsum, 16);
        lsum += __shfl_xor(lsum, 32);
        l_i = l_i * alpha + lsum;
        m_i = nm;

        // ---- write P (bf16) to per-wave LDS tile [q][key], packed b64
        #pragma unroll
        for (int c = 0; c < 4; c++) {
            bf16x4 pk;
            #pragma unroll
            for (int r = 0; r < 4; r++) pk[r] = (short)bf16bits(sv[c * 4 + r]);
            *(bf16x4*)&P_t[w][qq * 72 + c * 16 + quad * 4] = pk;
        }

        // ---- rescale O by alpha (per q = quad*4+r rows)
        #pragma unroll
        for (int r = 0; r < 4; r++) {
            const float ar = __shfl(alpha, quad * 4 + r);
            #pragma unroll
            for (int d = 0; d < 4; d++) O[d][r] *= ar;
        }

        // ---- PV: P (A) x V (B), keys in halves of 32
        const bf16x8 pf0 = *(const bf16x8*)&P_t[w][qq * 72 + quad * 8];
        const bf16x8 pf1 = *(const bf16x8*)&P_t[w][qq * 72 + 32 + quad * 8];
        #pragma unroll
        for (int d0 = 0; d0 < 4; d0++) {
            bf16x8 vf0 = *(const bf16x8*)&V_t[(d0 * 16 + qq) * 72 + quad * 8];
            bf16x8 vf1 = *(const bf16x8*)&V_t[(d0 * 16 + qq) * 72 + 32 + quad * 8];
            O[d0] = __builtin_amdgcn_mfma_f32_16x16x32_bf16(pf0, vf0, O[d0], 0, 0, 0);
            O[d0] = __builtin_amdgcn_mfma_f32_16x16x32_bf16(pf1, vf1, O[d0], 0, 0, 0);
        }
    }

    // ---- epilogue
    const float inv = 1.f / l_i;
    #pragma unroll
    for (int r = 0; r < 4; r++) {
        const float ir = __shfl(inv, quad * 4 + r);
        const int row = q0 + w * 16 + quad * 4 + r;
        __hip_bfloat16* op = outb + (size_t)(b * SS + row) * DD + (size_t)h * HD + qq;
        op[0]  = __float2bfloat16(O[0][r] * ir);
        op[16] = __float2bfloat16(O[1][r] * ir);
        op[32] = __float2bfloat16(O[2][r] * ir);
        op[48] = __float2bfloat16(O[3][r] * ir);
    }
}

// ---------------- residual add + layernorm ----------------------------------
__global__ __launch_bounds__(256) void ln_kernel(
        const float* __restrict__ a, const float* __restrict__ r,
        const float* __restrict__ g, const float* __restrict__ beta,
        float* __restrict__ outf, __hip_bfloat16* __restrict__ outb) {
    const int row = blockIdx.x;
    const int tid = threadIdx.x;
    __shared__ float red[64];

    float vals[3];
    float s = 0.f;
    #pragma unroll
    for (int i = 0; i < 3; i++) {
        const int col = i * 256 + tid;
        float t = a[(size_t)row * DD + col] + r[(size_t)row * DD + col];
        vals[i] = t;
        s += t;
    }
    const float mean = block_sum(s, red) * (1.f / DD);

    float s2 = 0.f;
    #pragma unroll
    for (int i = 0; i < 3; i++) {
        float d = vals[i] - mean;
        s2 += d * d;
    }
    const float var = block_sum(s2, red) * (1.f / DD);
    const float rstd = rsqrtf(var + LN_EPS);

    #pragma unroll
    for (int i = 0; i < 3; i++) {
        const int col = i * 256 + tid;
        const float o = (vals[i] - mean) * rstd * g[col] + beta[col];
        outf[(size_t)row * DD + col] = o;
        if (outb) outb[(size_t)row * DD + col] = __float2bfloat16(o);
    }
}

extern "C" void kernel_launch(void* const* d_in, const int* in_sizes, int n_in,
                              void* d_out, int out_size, void* d_ws, size_t ws_size,
                              hipStream_t stream) {
    const float* x     = (const float*)d_in[0];
    const float* alibi = (const float*)d_in[1];
    const float* Wq = (const float*)d_in[2];
    const float* bq = (const float*)d_in[3];
    const float* Wk = (const float*)d_in[4];
    const float* bk = (const float*)d_in[5];
    const float* Wv = (const float*)d_in[6];
    const float* bv = (const float*)d_in[7];
    const float* Wo = (const float*)d_in[8];
    const float* bo = (const float*)d_in[9];
    const float* W1 = (const float*)d_in[10];
    const float* b1 = (const float*)d_in[11];
    const float* W2 = (const float*)d_in[12];
    const float* b2 = (const float*)d_in[13];
    const float* g1 = (const float*)d_in[14];
    const float* be1 = (const float*)d_in[15];
    const float* g2 = (const float*)d_in[16];
    const float* be2 = (const float*)d_in[17];
    float* out = (float*)d_out;

    char* p = (char*)d_ws;
    auto alloc = [&](size_t bytes) { char* r = p; p += (bytes + 255) & ~(size_t)255; return r; };
    __hip_bfloat16* WqkvT = (__hip_bfloat16*)alloc((size_t)QLD * DD * 2);
    __hip_bfloat16* WoT   = (__hip_bfloat16*)alloc((size_t)DD * DD * 2);
    __hip_bfloat16* W1T   = (__hip_bfloat16*)alloc((size_t)DFF * DD * 2);
    __hip_bfloat16* W2T   = (__hip_bfloat16*)alloc((size_t)DD * DFF * 2);
    float*          biasc = (float*)alloc((size_t)QLD * 4);
    __hip_bfloat16* xb    = (__hip_bfloat16*)alloc((size_t)NROW * DD * 2);
    __hip_bfloat16* qkvb  = (__hip_bfloat16*)alloc((size_t)NROW * DFF * 2);
    __hip_bfloat16* attnb = (__hip_bfloat16*)alloc((size_t)NROW * DD * 2);
    float*          proj  = (float*)alloc((size_t)NROW * DD * 4);
    float*          ln1   = (float*)alloc((size_t)NROW * DD * 4);
    __hip_bfloat16* ln1b  = xb;
    __hip_bfloat16* ff1b  = qkvb;
    float*          ff2   = proj;

    const dim3 blk(256);

    transpose_bf16_kernel<<<dim3(DD / 32, DD / 32), blk, 0, stream>>>(Wq, WqkvT, DD, DD);
    transpose_bf16_kernel<<<dim3(DD / 32, DD / 32), blk, 0, stream>>>(Wk, WqkvT + (size_t)DD * DD, DD, DD);
    transpose_bf16_kernel<<<dim3(DD / 32, DD / 32), blk, 0, stream>>>(Wv, WqkvT + (size_t)2 * DD * DD, DD, DD);
    transpose_bf16_kernel<<<dim3(DD / 32, DD / 32), blk, 0, stream>>>(Wo, WoT, DD, DD);
    transpose_bf16_kernel<<<dim3(DFF / 32, DD / 32), blk, 0, stream>>>(W1, W1T, DD, DFF);
    transpose_bf16_kernel<<<dim3(DD / 32, DFF / 32), blk, 0, stream>>>(W2, W2T, DFF, DD);
    concat_bias_kernel<<<dim3((QLD + 255) / 256), blk, 0, stream>>>(bq, bk, bv, biasc);
    cvt_bf16_kernel<<<dim3(NROW * DD / 4 / 256), blk, 0, stream>>>(x, xb);

    mfma_gemm<128, 128><<<dim3(QLD / 128, NROW / 128), blk, 0, stream>>>(
            xb, WqkvT, biasc, nullptr, qkvb, QLD, DD, 0, 1, DD);

    flash_attn_kernel<<<dim3(SS / 64, HH, BB), blk, 0, stream>>>(qkvb, alibi, attnb);

    mfma_gemm<128, 64><<<dim3(DD / 64, NROW / 128), blk, 0, stream>>>(
            attnb, WoT, bo, proj, nullptr, DD, DD, 0, 0, 0);

    ln_kernel<<<dim3(NROW), blk, 0, stream>>>(x, proj, g1, be1, ln1, ln1b);

    mfma_gemm<128, 128><<<dim3(DFF / 128, NROW / 128), blk, 0, stream>>>(
            ln1b, W1T, b1, nullptr, ff1b, DFF, DD, 1, 1, 0);
    mfma_gemm<128, 64><<<dim3(DD / 64, NROW / 128), blk, 0, stream>>>(
            ff1b, W2T, b2, ff2, nullptr, DD, DFF, 0, 0, 0);

    ln_kernel<<<dim3(NROW), blk, 0, stream>>>(ln1, ff2, g2, be2, out, nullptr);
}